// Round 9
// baseline (2983.572 us; speedup 1.0000x reference)
//
#include <hip/hip_runtime.h>
#include <hip/hip_bf16.h>

#define Bsz 256
#define Nd  512
#define Hd  2048
#define Td  64
#define OFF_T (Bsz * Td * Nd)
#define OFF_L (OFF_T + Td)
#define LDU 514   // Ulds stride (elements)
#define LDZ 136   // Zlds stride

typedef __attribute__((ext_vector_type(8))) short short8;
typedef __attribute__((ext_vector_type(4))) float f32x4;

static __device__ __forceinline__ unsigned short f2bf(float x) {
  unsigned u = __builtin_bit_cast(unsigned, x);
  u += 0x7FFFu + ((u >> 16) & 1u);   // RNE
  return (unsigned short)(u >> 16);
}
static __device__ __forceinline__ float fast_tanh(float x) {
  float ex = __expf(2.0f * x);       // inf-safe
  return 1.0f - 2.0f / (ex + 1.0f);
}
// ---- agent-scope (sc1, LLC coherence point) primitives — the ONLY verified
// cross-block path on this part (live & correct rounds 3-6). No other cache
// semantics are used anywhere in this kernel.
static __device__ __forceinline__ unsigned long long lda64(const void* p) {
  return __hip_atomic_load((const unsigned long long*)p, __ATOMIC_RELAXED,
                           __HIP_MEMORY_SCOPE_AGENT);
}
static __device__ __forceinline__ void sta64(void* p, unsigned long long v) {
  __hip_atomic_store((unsigned long long*)p, v, __ATOMIC_RELAXED,
                     __HIP_MEMORY_SCOPE_AGENT);
}
static __device__ __forceinline__ unsigned lda32(const unsigned* p) {
  return __hip_atomic_load(p, __ATOMIC_RELAXED, __HIP_MEMORY_SCOPE_AGENT);
}
static __device__ __forceinline__ void sta32(unsigned* p, unsigned v) {
  __hip_atomic_store(p, v, __ATOMIC_RELAXED, __HIP_MEMORY_SCOPE_AGENT);
}

// 256 blocks x 256 threads (4 waves), 1 block/CU (LDS-forced).
// pod g = blk & 15 (16 blocks sharing batch rows g*16..g*16+15);
// il = blk >> 4: H-slice owner (GEMM1) / N-slice owner (GEMM2).
// Sync = single-writer monotonic flags (sta32) + relaxed polls (lda32).
__launch_bounds__(256, 1)
__global__ void ode_df(const float* __restrict__ y0g, const float* __restrict__ te,
                       const float* __restrict__ W1, const float* __restrict__ b1,
                       const float* __restrict__ W2, const float* __restrict__ b2,
                       float* __restrict__ out, unsigned* __restrict__ flagZ,
                       unsigned* __restrict__ flagK,
                       float* __restrict__ kS, unsigned short* __restrict__ Zg) {
  __shared__ unsigned short Ulds[16 * LDU];
  __shared__ unsigned short Zlds[16 * LDZ];
  __shared__ float red[4][16][33];
  __shared__ char spad[56 * 1024];   // occupancy limiter: 1 block/CU

  const int blk = blockIdx.x;
  const int g = blk & 15, il = blk >> 4;
  const int tid = threadIdx.x;
  const int wv = tid >> 6, lane = tid & 63;
  const int lr = lane & 15, lk = lane >> 4;

  if (te[0] == 1.0e30f) {            // never true; keeps spad allocated
    ((volatile char*)spad)[tid] = (char)tid;
    out[0] = ((volatile char*)spad)[0];
  }

  // ---------- one-time: resident weight fragments ----------
  short8 w1f[2][16];                 // W1 slice: cols il*128 + wv*32 + n*16 + lr
  {
    const int hbase = il * 128 + wv * 32;
    #pragma unroll
    for (int n = 0; n < 2; ++n) {
      const int col = hbase + n * 16 + lr;
      #pragma unroll
      for (int kt = 0; kt < 16; ++kt) {
        short8 v;
        #pragma unroll
        for (int jj = 0; jj < 8; ++jj)
          v[jj] = (short)f2bf(W1[(kt * 32 + lk * 8 + jj) * Hd + col]);
        w1f[n][kt] = v;
      }
    }
  }
  short8 w2f[2][16];                 // W2 slice: cols il*32 + n*16 + lr, K-chunk wv*512
  {
    #pragma unroll
    for (int n = 0; n < 2; ++n) {
      const int col = il * 32 + n * 16 + lr;
      #pragma unroll
      for (int kt = 0; kt < 16; ++kt) {
        short8 v;
        #pragma unroll
        for (int jj = 0; jj < 8; ++jj)
          v[jj] = (short)f2bf(W2[(wv * 512 + kt * 32 + lk * 8 + jj) * Nd + col]);
        w2f[n][kt] = v;
      }
    }
  }
  float b1c[2];
  b1c[0] = b1[il * 128 + wv * 32 + lr];
  b1c[1] = b1[il * 128 + wv * 32 + 16 + lr];

  // ---------- per-thread state mapping ----------
  const int r  = tid >> 4;
  const int cq = tid & 15;
  const int cb = cq * 32;
  const int rowg = g * 16 + r;
  const int c2 = (tid & 15) * 2;
  const int rowe = tid >> 4;
  const float b2e0 = b2[il * 32 + c2], b2e1 = b2[il * 32 + c2 + 1];

  float yv[32];
  #pragma unroll
  for (int gg = 0; gg < 8; ++gg) {
    f32x4 v = *(const f32x4*)&y0g[rowg * Nd + cb + gg * 4];
    yv[gg * 4 + 0] = v[0]; yv[gg * 4 + 1] = v[1];
    yv[gg * 4 + 2] = v[2]; yv[gg * 4 + 3] = v[3];
  }
  float acc_y[32];
  #pragma unroll
  for (int p = 0; p < 32; ++p) acc_y[p] = 0.0f;

  // ---------- pre-loop outputs ----------
  if (cq == il) {
    #pragma unroll
    for (int gg = 0; gg < 8; ++gg) {
      f32x4 v = {yv[gg * 4], yv[gg * 4 + 1], yv[gg * 4 + 2], yv[gg * 4 + 3]};
      *(f32x4*)&out[rowg * (Td * Nd) + cb + gg * 4] = v;
    }
  }
  if (blk == 0) {
    if (tid < Td) out[OFF_T + tid] = te[tid];
    out[OFF_L + tid] = 0.0f;
  }

  unsigned* flZ = flagZ + g * 16;    // pod's 16 Z-flags, one 64B line
  unsigned* flK = flagK + g * 16;    // pod's 16 k-flags, one 64B line

  // ---------- main loop: 63 steps x 4 evals ----------
  int j = 0;
  for (int t = 0; t < Td - 1; ++t) {
    const float h = te[t + 1] - te[t];
    for (int e = 1; e <= 4; ++e) {
      // ---- wait for k(j-1) from all pod members, then load ----
      float kv[32];
      if (!(e == 1 && t == 0)) {
        const unsigned tgt = (unsigned)j;           // flagK == j after eval j-1
        const unsigned* p = flK + (tid & 15);       // 64 lanes cover the 16-word line
        for (;;) {
          unsigned v = lda32(p);
          if (__all((int)(v >= tgt))) break;
          __builtin_amdgcn_s_sleep(1);
        }
        const float* kbase = &kS[rowg * Nd + cb];
        #pragma unroll
        for (int p2 = 0; p2 < 16; ++p2) {
          unsigned long long q = lda64(kbase + p2 * 2);
          kv[2 * p2 + 0] = __builtin_bit_cast(float, (unsigned)(q & 0xFFFFFFFFull));
          kv[2 * p2 + 1] = __builtin_bit_cast(float, (unsigned)(q >> 32));
        }
      }
      // ---- U phase ----
      if (e == 1) {
        if (t > 0) {
          const float hp6 = (te[t] - te[t - 1]) * (1.0f / 6.0f);
          #pragma unroll
          for (int p2 = 0; p2 < 32; ++p2) yv[p2] += hp6 * (acc_y[p2] + kv[p2]);
          if (cq == il) {
            #pragma unroll
            for (int gg = 0; gg < 8; ++gg) {
              f32x4 v = {yv[gg * 4], yv[gg * 4 + 1], yv[gg * 4 + 2], yv[gg * 4 + 3]};
              *(f32x4*)&out[rowg * (Td * Nd) + t * Nd + cb + gg * 4] = v;
            }
          }
        }
        #pragma unroll
        for (int p2 = 0; p2 < 32; ++p2) acc_y[p2] = 0.0f;
        #pragma unroll
        for (int gg = 0; gg < 4; ++gg) {
          short8 s;
          #pragma unroll
          for (int p2 = 0; p2 < 8; ++p2) s[p2] = (short)f2bf(yv[gg * 8 + p2]);
          *(short8*)&Ulds[r * LDU + cb + gg * 8] = s;
        }
      } else {
        const float c = (e == 4) ? h : 0.5f * h;
        const float w = (e == 2) ? 1.0f : 2.0f;
        #pragma unroll
        for (int gg = 0; gg < 4; ++gg) {
          short8 s;
          #pragma unroll
          for (int p2 = 0; p2 < 8; ++p2) {
            const int idx = gg * 8 + p2;
            acc_y[idx] += w * kv[idx];
            s[p2] = (short)f2bf(yv[idx] + c * kv[idx]);
          }
          *(short8*)&Ulds[r * LDU + cb + gg * 8] = s;
        }
      }
      __syncthreads();

      // ---- GEMM1: [16,512] @ W1-slice ----
      f32x4 acc1_0 = {0.f, 0.f, 0.f, 0.f}, acc1_1 = {0.f, 0.f, 0.f, 0.f};
      {
        const int abase = lr * LDU + lk * 8;
        #pragma unroll
        for (int kt = 0; kt < 16; ++kt) {
          short8 a = *(const short8*)&Ulds[abase + kt * 32];
          acc1_0 = __builtin_amdgcn_mfma_f32_16x16x32_bf16(a, w1f[0][kt], acc1_0, 0, 0, 0);
          acc1_1 = __builtin_amdgcn_mfma_f32_16x16x32_bf16(a, w1f[1][kt], acc1_1, 0, 0, 0);
        }
      }
      #pragma unroll
      for (int n = 0; n < 2; ++n) {
        f32x4 a = n ? acc1_1 : acc1_0;
        #pragma unroll
        for (int q = 0; q < 4; ++q)
          Zlds[(lk * 4 + q) * LDZ + wv * 32 + n * 16 + lr] = f2bf(fast_tanh(a[q] + b1c[n]));
      }
      __syncthreads();
      // ---- export Z[16,128] (agent stores -> LLC) ----
      #pragma unroll
      for (int u = 0; u < 2; ++u) {
        int idx = tid + u * 256;
        int zr = idx >> 5, zc4 = idx & 31;
        unsigned long long v = *(const unsigned long long*)&Zlds[zr * LDZ + zc4 * 4];
        sta64(&Zg[(g * 16 + zr) * Hd + il * 128 + zc4 * 4], v);
      }
      __syncthreads();                         // vmcnt(0) drain: Z at LLC
      if (tid == 0) sta32(&flZ[il], (unsigned)(j + 1));

      // ---- GEMM2: per-member dataflow (wave wv consumes members wv*4+q) ----
      f32x4 acc2_0 = {0.f, 0.f, 0.f, 0.f}, acc2_1 = {0.f, 0.f, 0.f, 0.f};
      {
        const unsigned zt = (unsigned)(j + 1);
        const unsigned short* zp = &Zg[(g * 16 + lr) * Hd + wv * 512 + lk * 8];
        #pragma unroll
        for (int q = 0; q < 4; ++q) {
          const unsigned* fz = &flZ[wv * 4 + q];   // uniform per wave
          while (lda32(fz) < zt) __builtin_amdgcn_s_sleep(1);
          #pragma unroll
          for (int k2 = 0; k2 < 4; ++k2) {
            const int kt = q * 4 + k2;
            union { unsigned long long q2[2]; short8 s; } az_;
            az_.q2[0] = lda64(zp + kt * 32);
            az_.q2[1] = lda64(zp + kt * 32 + 4);
            acc2_0 = __builtin_amdgcn_mfma_f32_16x16x32_bf16(az_.s, w2f[0][kt], acc2_0, 0, 0, 0);
            acc2_1 = __builtin_amdgcn_mfma_f32_16x16x32_bf16(az_.s, w2f[1][kt], acc2_1, 0, 0, 0);
          }
        }
      }
      // ---- deterministic cross-wave reduce ----
      #pragma unroll
      for (int q = 0; q < 4; ++q) {
        red[wv][lk * 4 + q][lr]      = acc2_0[q];
        red[wv][lk * 4 + q][16 + lr] = acc2_1[q];
      }
      __syncthreads();
      {
        float s0 = red[0][rowe][c2] + red[1][rowe][c2] + red[2][rowe][c2] + red[3][rowe][c2] + b2e0;
        float s1 = red[0][rowe][c2 + 1] + red[1][rowe][c2 + 1] + red[2][rowe][c2 + 1] + red[3][rowe][c2 + 1] + b2e1;
        unsigned long long pk =
            ((unsigned long long)__builtin_bit_cast(unsigned, s1) << 32) |
            __builtin_bit_cast(unsigned, s0);
        sta64(&kS[(g * 16 + rowe) * Nd + il * 32 + c2], pk);
      }
      __syncthreads();                         // vmcnt(0) drain: k at LLC
      if (tid == 0) sta32(&flK[il], (unsigned)(j + 1));
      ++j;
    }
  }

  // ---------- epilogue: final y-update + y_t[:, 63, :] ----------
  {
    const unsigned tgt = (unsigned)j;          // j == 252
    const unsigned* p = flK + (tid & 15);
    for (;;) {
      unsigned v = lda32(p);
      if (__all((int)(v >= tgt))) break;
      __builtin_amdgcn_s_sleep(1);
    }
    float kv[32];
    const float* kbase = &kS[rowg * Nd + cb];
    #pragma unroll
    for (int p2 = 0; p2 < 16; ++p2) {
      unsigned long long q = lda64(kbase + p2 * 2);
      kv[2 * p2 + 0] = __builtin_bit_cast(float, (unsigned)(q & 0xFFFFFFFFull));
      kv[2 * p2 + 1] = __builtin_bit_cast(float, (unsigned)(q >> 32));
    }
    const float hp6 = (te[Td - 1] - te[Td - 2]) * (1.0f / 6.0f);
    #pragma unroll
    for (int p2 = 0; p2 < 32; ++p2) yv[p2] += hp6 * (acc_y[p2] + kv[p2]);
    if (cq == il) {
      #pragma unroll
      for (int gg = 0; gg < 8; ++gg) {
        f32x4 v = {yv[gg * 4], yv[gg * 4 + 1], yv[gg * 4 + 2], yv[gg * 4 + 3]};
        *(f32x4*)&out[rowg * (Td * Nd) + (Td - 1) * Nd + cb + gg * 4] = v;
      }
    }
  }
}

extern "C" void kernel_launch(void* const* d_in, const int* in_sizes, int n_in,
                              void* d_out, int out_size, void* d_ws, size_t ws_size,
                              hipStream_t stream) {
  const float* y0 = (const float*)d_in[0];
  const float* te = (const float*)d_in[1];
  const float* W1 = (const float*)d_in[2];
  const float* b1 = (const float*)d_in[3];
  const float* W2 = (const float*)d_in[4];
  const float* b2 = (const float*)d_in[5];
  float* out = (float*)d_out;

  char* p = (char*)d_ws;
  unsigned* flagZ = (unsigned*)p;                 // 1 KB: 16 pods x 16 flags
  unsigned* flagK = (unsigned*)(p + 1024);        // 1 KB
  float* kS = (float*)(p + 4096);                 // 512 KB
  unsigned short* Zg = (unsigned short*)(p + 4096 + 512 * 1024);  // 1 MB

  hipMemsetAsync(d_ws, 0, 4096, stream);          // zero all flags each launch
  ode_df<<<dim3(256), dim3(256), 0, stream>>>(y0, te, W1, b1, W2, b2, out,
                                              flagZ, flagK, kS, Zg);
}